// Round 2
// baseline (5051.958 us; speedup 1.0000x reference)
//
#include <hip/hip_runtime.h>

#define TT 128
#define INF 171

typedef _Float16 half8 __attribute__((ext_vector_type(8)));
typedef float floatx4 __attribute__((ext_vector_type(4)));
typedef unsigned short u16;

#define XBSZ 163840   // 8 btiles * 40 kc * 512
#define HSZ  131072   // 8 btiles * 32 kc * 512

__device__ __forceinline__ u16 f2h(float f){
  _Float16 h = (_Float16)f;
  return __builtin_bit_cast(u16, h);
}
__device__ __forceinline__ float sigm(float x){ return 1.f/(1.f+__expf(-x)); }
__device__ __forceinline__ float tanh_(float x){ return 1.f - 2.f/(__expf(2.f*x)+1.f); }

// coherent (L1+L2-bypass, LLC-visible) scatter store of one fp16 value
// layout: [btile][kchunk(nch)][lane(64)][8] ; lane = ((k>>3)&3)*16 + (b&15), elem = k&7
__device__ __forceinline__ void scat_coh(u16* buf, int nch, int b, int k, u16 v){
  u16* p = buf + (size_t)((((b>>4)*nch + (k>>5))*4 + ((k>>3)&3))*16 + (b&15))*8 + (k&7);
  unsigned int vv = v;
  asm volatile("global_store_short %0, %1, off sc0 sc1" :: "v"(p), "v"(vv) : "memory");
}
// coherent 16B load (bypasses L1+L2, reads current LLC truth)
__device__ __forceinline__ void ld16_coh(half8& d, const u16* p){
  asm volatile("global_load_dwordx4 %0, %1, off sc0 sc1" : "=&v"(d) : "v"(p) : "memory");
}

// ---------------- weight prep (fragment-swizzled fp16) ----------------
__global__ __launch_bounds__(256) void prep_w1f(const float* __restrict__ Wih1,
    const float* __restrict__ Whh1, u16* __restrict__ Wf){
  int u = blockIdx.x*256 + threadIdx.x;          // exactly 655360 units
  int tile = u / 2560;
  int r = u - tile*2560;
  int kc = r >> 6, l = r & 63;
  int row = (tile>>6)*1024 + (tile&63)*16 + (l&15);
  int k0 = kc*32 + ((l>>4)<<3);
  half8 hv;
  #pragma unroll
  for (int e=0;e<8;e++){
    int k = k0+e;
    float w = 0.f;
    if (k < 171)       w = Wih1[(size_t)row*171 + k];
    else if (k < 1195) w = Whh1[(size_t)row*1024 + (k-171)];
    hv[e] = (_Float16)w;
  }
  *(half8*)&Wf[(size_t)(tile*40 + kc)*512 + (size_t)l*8] = hv;
}

__global__ __launch_bounds__(256) void prep_w23f(const float* __restrict__ Wih2,
    const float* __restrict__ Whh2, const float* __restrict__ Wih3,
    const float* __restrict__ Whh3, u16* __restrict__ W2f, u16* __restrict__ W3f){
  int u = blockIdx.x*256 + threadIdx.x;          // exactly 1048576 units
  int tile = u >> 12;
  int r = u & 4095;
  int kc = r >> 6, l = r & 63;
  int row = (tile>>6)*1024 + (tile&63)*16 + (l&15);
  int k0 = kc*32 + ((l>>4)<<3);
  half8 h2, h3;
  #pragma unroll
  for (int e=0;e<8;e++){
    int k = k0+e;
    size_t si = (size_t)row*1024 + (k & 1023);
    h2[e] = (_Float16)((k < 1024) ? Wih2[si] : Whh2[si]);
    h3[e] = (_Float16)((k < 1024) ? Wih3[si] : Whh3[si]);
  }
  size_t base = (size_t)(tile*64 + kc)*512 + (size_t)l*8;
  *(half8*)&W2f[base] = h2;
  *(half8*)&W3f[base] = h3;
}

__global__ __launch_bounds__(256) void prep_wdecf(const float* __restrict__ Wdec,
    u16* __restrict__ Wdf){
  int u = blockIdx.x*256 + threadIdx.x;          // exactly 22528 units
  int tile = u / 2048;
  int r = u & 2047;
  int kc = r >> 6, l = r & 63;
  int row = tile*16 + (l&15);
  int k0 = kc*32 + ((l>>4)<<3);
  half8 hv;
  #pragma unroll
  for (int e=0;e<8;e++){
    int k = k0+e;
    hv[e] = (_Float16)((row < 171) ? Wdec[(size_t)row*1024 + k] : 0.f);
  }
  *(half8*)&Wdf[(size_t)(tile*32 + kc)*512 + (size_t)l*8] = hv;
}

// biases + activation-buffer init (+ step-0 frame) + c init + barrier counters
__global__ __launch_bounds__(256) void prep_misc(
    const float* __restrict__ rseq, const int* __restrict__ gnp,
    const float* __restrict__ bih1, const float* __restrict__ bhh1,
    const float* __restrict__ bih2, const float* __restrict__ bhh2,
    const float* __restrict__ bih3, const float* __restrict__ bhh3,
    const float* __restrict__ bdec,
    u16* __restrict__ Xb1f, u16* __restrict__ Hf, float* __restrict__ cbuf,
    float* __restrict__ b1, float* __restrict__ b2, float* __restrict__ b3,
    float* __restrict__ bd, int* __restrict__ bar)
{
  size_t idx = (size_t)blockIdx.x*256 + threadIdx.x;
  if (idx < 327680){                       // Xb1f: 2 parities x [8][40][512]
    int q = (int)(idx / 163840);
    int rem = (int)(idx % 163840);
    int btile = rem / 20480;
    int r2 = rem % 20480;
    int kc = r2 >> 9, r3 = r2 & 511;
    int l = r3 >> 3, e = r3 & 7;
    int b = btile*16 + (l&15);
    int k = kc*32 + ((l>>4)<<3) + e;
    float v = 0.f;
    if (q==0 && k < 171 && *gnp > 0) v = rseq[(size_t)b*TT*INF + k];
    Xb1f[idx] = f2h(v);
    return;
  }
  idx -= 327680;
  if (idx < 786432){ Hf[idx] = 0; return; }        // H0/H1/H2 x 2 parities
  idx -= 786432;
  if (idx < 393216){ cbuf[idx] = 0.f; return; }    // c0,c1,c2 (unused now, harmless)
  idx -= 393216;
  if (idx < 12288){
    int which = (int)(idx >> 12), j = (int)(idx & 4095);
    float v = (which==0)? (bih1[j]+bhh1[j]) : (which==1)? (bih2[j]+bhh2[j]) : (bih3[j]+bhh3[j]);
    ((which==0)?b1:(which==1)?b2:b3)[j] = v;
    return;
  }
  idx -= 12288;
  if (idx < 176){ bd[idx] = (idx < 171) ? bdec[idx] : 0.f; return; }
  idx -= 176;
  if (idx < 512) bar[idx] = 0;
}

// ---------------- grid barrier: FENCE-FREE -----------------------------------
// All cross-block data moves via sc0|sc1 (LLC-coherent) accesses, so no L2
// writeback/invalidate is needed. Ordering: every thread drains vmcnt(0)
// (sc1 stores acked at LLC) before s_barrier; leader's relaxed LLC atomics
// then happen-after; readers' sc1 loads issue after the data-dependent spin.
__device__ __forceinline__ void gridbar(int* __restrict__ bar, int bId, int bc, int* s_dead){
  asm volatile("s_waitcnt vmcnt(0)" ::: "memory");
  __syncthreads();
  if (threadIdx.x == 0 && !(*s_dead)){
    int* c1  = &bar[(bId & 7) * 32];
    int* c0  = &bar[288];
    int* gen = &bar[320];
    bool released = false;
    int o1 = __hip_atomic_fetch_add(c1, 1, __ATOMIC_RELAXED, __HIP_MEMORY_SCOPE_AGENT);
    if ((o1 & 31) == 31){
      int o0 = __hip_atomic_fetch_add(c0, 1, __ATOMIC_RELAXED, __HIP_MEMORY_SCOPE_AGENT);
      if ((o0 & 7) == 7){
        __hip_atomic_fetch_add(gen, 1, __ATOMIC_RELAXED, __HIP_MEMORY_SCOPE_AGENT);
        released = true;
      }
    }
    if (!released){
      long long t0 = clock64();
      while (__hip_atomic_fetch_add(gen, 0, __ATOMIC_RELAXED, __HIP_MEMORY_SCOPE_AGENT) < bc + 1){
        __builtin_amdgcn_s_sleep(2);
        if (clock64() - t0 > 30000000LL){ *s_dead = 1; break; }  // ~12ms escape
      }
    }
  }
  __syncthreads();
}

// ---------------- coherent global->LDS stage ---------------------------------
// NC chunks, NBC 8KB-beats per chunk; each thread copies 16B per beat.
// asm-issue all loads -> one vmcnt(0) -> sched_barrier(0) -> ds_writes
// (rule: compiler must not hoist uses past the asm waitcnt).
template<int NC, int NBC>
__device__ __forceinline__ void stage(const u16* const* srcs, u16* XL, int tid){
  half8 v[NC*NBC];
  #pragma unroll
  for (int c=0;c<NC;c++){
    #pragma unroll
    for (int i=0;i<NBC;i++)
      ld16_coh(v[c*NBC+i], srcs[c] + (size_t)i*4096 + (size_t)tid*8);
  }
  asm volatile("s_waitcnt vmcnt(0)" ::: "memory");
  __builtin_amdgcn_sched_barrier(0);
  #pragma unroll
  for (int c=0;c<NC;c++){
    #pragma unroll
    for (int i=0;i<NBC;i++)
      *(half8*)&XL[(size_t)(c*NBC+i)*4096 + (size_t)tid*8] = v[c*NBC+i];
  }
}

// ---------------- half-K GEMM: W streamed (L2-resident), X from LDS ----------
template<int KHALF, int GS>
__device__ __forceinline__ void gemm_stream(const u16* __restrict__ wp,
    const u16* __restrict__ x0, const u16* __restrict__ x1,
    floatx4& a0, floatx4& a1)
{
  constexpr int NG = KHALF/GS;
  half8 W[2][GS];
  #pragma unroll
  for (int i=0;i<GS;i++)
    W[0][i] = *(const half8*)(wp + (size_t)i*512);
  #pragma unroll
  for (int g8=0; g8<NG; g8++){
    const int cur = g8 & 1, nxt = cur ^ 1;
    if (g8+1 < NG){
      const size_t off = (size_t)(g8+1)*GS*512;
      #pragma unroll
      for (int i=0;i<GS;i++)
        W[nxt][i] = *(const half8*)(wp + off + (size_t)i*512);
    }
    #pragma unroll
    for (int i=0;i<GS;i++){
      half8 xv0 = *(const half8*)(x0 + (size_t)(g8*GS+i)*512);
      half8 xv1 = *(const half8*)(x1 + (size_t)(g8*GS+i)*512);
      a0 = __builtin_amdgcn_mfma_f32_16x16x32_f16(W[cur][i], xv0, a0, 0,0,0);
      a1 = __builtin_amdgcn_mfma_f32_16x16x32_f16(W[cur][i], xv1, a1, 0,0,0);
    }
  }
}

// ---------------- persistent kernel: 256 blocks x 512 threads ----------------
// Block = (js 16 units, nq 32 batch). 8 waves: wave w -> gate (w>>1), K-half (w&1).
// W1 + W2 + Wdec slices live in VGPRs for the whole kernel (time-invariant);
// W3 streams through L2 (per-XCD W3 footprint 2MB < 4MB L2, now that W1/W2
// no longer compete). Cell state c and biases are per-thread registers.
__global__ void __launch_bounds__(512,2) acro_persist(
    const u16* __restrict__ W1f, const u16* __restrict__ W2f,
    const u16* __restrict__ W3f, const u16* __restrict__ Wdf,
    u16* __restrict__ Xb1f, u16* __restrict__ Hf,
    const float* __restrict__ b1, const float* __restrict__ b2,
    const float* __restrict__ b3, const float* __restrict__ bd,
    const float* __restrict__ rseq, float* __restrict__ out,
    const int* __restrict__ cnp, const int* __restrict__ gnp, int* __restrict__ bar)
{
  __shared__ u16 XL[65536];           // 128 KiB activation stage
  __shared__ float gb[8][16][33];     // per-wave partials (+1 pad)
  __shared__ int s_dead;
  const int bId = (int)blockIdx.x;
  const int js = (bId & 7)*8 + ((bId >> 5) & 7);   // 4 nq-siblings share XCD class
  const int nq = (bId >> 3) & 3;
  const int tid = (int)threadIdx.x;
  const int w = tid >> 6, l = tid & 63;
  const int g = w >> 1, hf = w & 1;
  const int l15 = l & 15, lq = l >> 4;
  const int uu = tid >> 5, bq = tid & 31;
  const int jj = js*16 + uu, bgg = nq*32 + bq;
  if (tid == 0) s_dead = 0;
  const int gnv = *gnp;
  int P = *cnp + gnv; if (P < 1) P = 1;
  int bc = 0;                          // barriers completed

  u16* H0[2] = { Hf,          Hf + HSZ   };
  u16* H1[2] = { Hf + 2*HSZ,  Hf + 3*HSZ };
  u16* H2[2] = { Hf + 4*HSZ,  Hf + 5*HSZ };

  // ---- persistent register state: weights, biases, cell state ----
  half8 W1r[20], W2r[32], Wdr[4];
  {
    const u16* wp = W1f + ((size_t)(g*64 + js)*40 + (size_t)hf*20)*512 + (size_t)(l<<3);
    #pragma unroll
    for (int i=0;i<20;i++) W1r[i] = *(const half8*)(wp + (size_t)i*512);
  }
  {
    const u16* wp = W2f + ((size_t)(g*64 + js)*64 + (size_t)hf*32)*512 + (size_t)(l<<3);
    #pragma unroll
    for (int i=0;i<32;i++) W2r[i] = *(const half8*)(wp + (size_t)i*512);
  }
  const int dtile = bId >> 2, dq_ = bId & 3;
  const int oo = dtile*16 + uu;
  if (bId < 44){
    const u16* wp = Wdf + (size_t)(dtile*32 + w*4)*512 + (size_t)(l<<3);
    #pragma unroll
    for (int i=0;i<4;i++) Wdr[i] = *(const half8*)(wp + (size_t)i*512);
  } else {
    #pragma unroll
    for (int i=0;i<4;i++) Wdr[i] = half8{};
  }
  float bs1[4], bs2[4], bs3[4];
  #pragma unroll
  for (int q=0;q<4;q++){
    bs1[q] = b1[q*1024 + jj];
    bs2[q] = b2[q*1024 + jj];
    bs3[q] = b3[q*1024 + jj];
  }
  const float bdr = (bId < 44) ? bd[oo] : 0.f;   // bd padded to 176
  float c0r = 0.f, c1r = 0.f, c2r = 0.f;

  __syncthreads();
  for (int t=0; t<TT; t++){
    const int pr = t & 1, nx = pr ^ 1;

    // ============ L1: x = [frame | h0(t-1)], 40 kc, halves of 20, W in regs ==
    {
      const u16* xb = Xb1f + (size_t)pr*XBSZ;
      const u16* srcs[2] = { xb + (size_t)(nq*2)*20480, xb + (size_t)(nq*2+1)*20480 };
      stage<2,5>(srcs, XL, tid);
      __syncthreads();
      const u16* x0 = XL + (size_t)hf*10240 + (size_t)(l<<3);
      const u16* x1 = x0 + 20480;
      floatx4 a0{}, a1{};
      #pragma unroll
      for (int i=0;i<20;i++){
        half8 xv0 = *(const half8*)(x0 + (size_t)i*512);
        half8 xv1 = *(const half8*)(x1 + (size_t)i*512);
        a0 = __builtin_amdgcn_mfma_f32_16x16x32_f16(W1r[i], xv0, a0, 0,0,0);
        a1 = __builtin_amdgcn_mfma_f32_16x16x32_f16(W1r[i], xv1, a1, 0,0,0);
      }
      #pragma unroll
      for (int r=0;r<4;r++){
        gb[w][lq*4+r][l15]      = a0[r];
        gb[w][lq*4+r][16 + l15] = a1[r];
      }
      __syncthreads();
      {
        float gi = gb[0][uu][bq] + gb[1][uu][bq] + bs1[0];
        float gf = gb[2][uu][bq] + gb[3][uu][bq] + bs1[1];
        float gg = gb[4][uu][bq] + gb[5][uu][bq] + bs1[2];
        float go = gb[6][uu][bq] + gb[7][uu][bq] + bs1[3];
        float c = sigm(gf)*c0r + sigm(gi)*tanh_(gg);
        c0r = c;
        u16 hb = f2h(sigm(go)*tanh_(c));
        scat_coh(H0[pr], 32, bgg, jj, hb);
        scat_coh(Xb1f + (size_t)nx*XBSZ, 40, bgg, 171 + jj, hb);
      }
    }
    gridbar(bar, bId, bc, &s_dead); bc++;

    // ============ L2: x = [h0(t) | h1(t-1)], 64 kc, W2 in regs ==============
    {
      const u16* xa = H0[pr];
      const u16* xh = H1[nx];
      const u16* srcs[4] = {
        xa + (size_t)(nq*2  )*16384, xa + (size_t)(nq*2+1)*16384,
        xh + (size_t)(nq*2  )*16384, xh + (size_t)(nq*2+1)*16384 };
      stage<4,4>(srcs, XL, tid);
      __syncthreads();
      const u16* x0 = XL + (size_t)hf*32768 + (size_t)(l<<3);
      const u16* x1 = x0 + 16384;
      floatx4 a0{}, a1{};
      #pragma unroll
      for (int i=0;i<32;i++){
        half8 xv0 = *(const half8*)(x0 + (size_t)i*512);
        half8 xv1 = *(const half8*)(x1 + (size_t)i*512);
        a0 = __builtin_amdgcn_mfma_f32_16x16x32_f16(W2r[i], xv0, a0, 0,0,0);
        a1 = __builtin_amdgcn_mfma_f32_16x16x32_f16(W2r[i], xv1, a1, 0,0,0);
      }
      #pragma unroll
      for (int r=0;r<4;r++){
        gb[w][lq*4+r][l15]      = a0[r];
        gb[w][lq*4+r][16 + l15] = a1[r];
      }
      __syncthreads();
      {
        float gi = gb[0][uu][bq] + gb[1][uu][bq] + bs2[0];
        float gf = gb[2][uu][bq] + gb[3][uu][bq] + bs2[1];
        float gg = gb[4][uu][bq] + gb[5][uu][bq] + bs2[2];
        float go = gb[6][uu][bq] + gb[7][uu][bq] + bs2[3];
        float c = sigm(gf)*c1r + sigm(gi)*tanh_(gg);
        c1r = c;
        u16 hb = f2h(sigm(go)*tanh_(c));
        scat_coh(H1[pr], 32, bgg, jj, hb);
      }
    }
    gridbar(bar, bId, bc, &s_dead); bc++;

    // ============ L3: x = [h1(t) | h2(t-1)], 64 kc, W3 streamed (L2-hit) ====
    {
      const u16* xa = H1[pr];
      const u16* xh = H2[nx];
      const u16* srcs[4] = {
        xa + (size_t)(nq*2  )*16384, xa + (size_t)(nq*2+1)*16384,
        xh + (size_t)(nq*2  )*16384, xh + (size_t)(nq*2+1)*16384 };
      stage<4,4>(srcs, XL, tid);
      __syncthreads();
      const u16* wp = W3f + ((size_t)(g*64 + js)*64 + (size_t)hf*32)*512 + (size_t)(l<<3);
      const u16* x0 = XL + (size_t)hf*32768 + (size_t)(l<<3);
      const u16* x1 = x0 + 16384;
      floatx4 a0{}, a1{};
      gemm_stream<32,8>(wp, x0, x1, a0, a1);
      #pragma unroll
      for (int r=0;r<4;r++){
        gb[w][lq*4+r][l15]      = a0[r];
        gb[w][lq*4+r][16 + l15] = a1[r];
      }
      __syncthreads();
      {
        float gi = gb[0][uu][bq] + gb[1][uu][bq] + bs3[0];
        float gf = gb[2][uu][bq] + gb[3][uu][bq] + bs3[1];
        float gg = gb[4][uu][bq] + gb[5][uu][bq] + bs3[2];
        float go = gb[6][uu][bq] + gb[7][uu][bq] + bs3[3];
        float c = sigm(gf)*c2r + sigm(gi)*tanh_(gg);
        c2r = c;
        u16 hb = f2h(sigm(go)*tanh_(c));
        scat_coh(H2[pr], 32, bgg, jj, hb);
      }
    }
    gridbar(bar, bId, bc, &s_dead); bc++;

    // ============ dec: blocks 0..43 = (tile, dq); waves split K 8 ways =======
    if (bId < 44){
      const u16* srcs[2] = { H2[pr] + (size_t)(dq_*2)*16384, H2[pr] + (size_t)(dq_*2+1)*16384 };
      stage<2,4>(srcs, XL, tid);
      __syncthreads();
      const u16* x0 = XL + (size_t)(w*4)*512 + (size_t)(l<<3);
      const u16* x1 = x0 + 16384;
      floatx4 d0{}, d1{};
      #pragma unroll
      for (int i=0;i<4;i++){
        half8 a0v = *(const half8*)(x0 + (size_t)i*512);
        half8 a1v = *(const half8*)(x1 + (size_t)i*512);
        d0 = __builtin_amdgcn_mfma_f32_16x16x32_f16(Wdr[i], a0v, d0, 0,0,0);
        d1 = __builtin_amdgcn_mfma_f32_16x16x32_f16(Wdr[i], a1v, d1, 0,0,0);
      }
      #pragma unroll
      for (int r=0;r<4;r++){
        gb[w][lq*4+r][l15]      = d0[r];
        gb[w][lq*4+r][16 + l15] = d1[r];
      }
      __syncthreads();
      const int nf = (((t+1) % P) < gnv) ? 1 : 0;
      if (oo < 171){
        float v = bdr;
        #pragma unroll
        for (int i=0;i<8;i++) v += gb[i][uu][bq];
        int b = dq_*32 + bq;
        out[((size_t)b*TT + t)*INF + oo] = v;
        if (t+1 < TT){
          float src = nf ? rseq[((size_t)b*TT + (t+1))*INF + oo] : v;
          scat_coh(Xb1f + (size_t)nx*XBSZ, 40, b, oo, f2h(src));
        }
      }
    }
    gridbar(bar, bId, bc, &s_dead); bc++;
  }
}

// ---------------- host ----------------
extern "C" void kernel_launch(void* const* d_in, const int* in_sizes, int n_in,
                              void* d_out, int out_size, void* d_ws, size_t ws_size,
                              hipStream_t stream)
{
  const float* rseq = (const float*)d_in[0];
  const float* Wih1 = (const float*)d_in[1];
  const float* Whh1 = (const float*)d_in[2];
  const float* bih1 = (const float*)d_in[3];
  const float* bhh1 = (const float*)d_in[4];
  const float* Wih2 = (const float*)d_in[5];
  const float* Whh2 = (const float*)d_in[6];
  const float* bih2 = (const float*)d_in[7];
  const float* bhh2 = (const float*)d_in[8];
  const float* Wih3 = (const float*)d_in[9];
  const float* Whh3 = (const float*)d_in[10];
  const float* bih3 = (const float*)d_in[11];
  const float* bhh3 = (const float*)d_in[12];
  const float* Wdec = (const float*)d_in[13];
  const float* bdec = (const float*)d_in[14];
  const int* cn = (const int*)d_in[15];
  const int* gn = (const int*)d_in[16];
  float* out = (float*)d_out;

  char* p = (char*)d_ws;
  auto take = [&](size_t n){ void* r = (void*)p; p += (n + 255) & ~(size_t)255; return r; };
  u16* W1f  = (u16*)take(5242880UL*2);      // 256*40*512
  u16* W2f  = (u16*)take(8388608UL*2);      // 256*64*512
  u16* W3f  = (u16*)take(8388608UL*2);
  u16* Wdf  = (u16*)take(180224UL*2);       // 11*32*512
  u16* Xb1f = (u16*)take(327680UL*2);       // 2 parities x [8][40][512]
  u16* Hf   = (u16*)take(786432UL*2);       // 6 x [8][32][512]
  float* cbuf = (float*)take(393216UL*4);   // (kept for prep_misc; unused by persist)
  float* b1 = (float*)take(4096*4);
  float* b2 = (float*)take(4096*4);
  float* b3 = (float*)take(4096*4);
  float* bd = (float*)take(176*4);
  int* bar  = (int*)take(512*4);
  if ((size_t)(p - (char*)d_ws) > ws_size) return;

  prep_w1f  <<<2560,256,0,stream>>>(Wih1, Whh1, W1f);
  prep_w23f <<<4096,256,0,stream>>>(Wih2, Whh2, Wih3, Whh3, W2f, W3f);
  prep_wdecf<<<88,  256,0,stream>>>(Wdec, Wdf);
  prep_misc <<<5939,256,0,stream>>>(rseq, gn, bih1,bhh1,bih2,bhh2,bih3,bhh3,bdec,
                                    Xb1f, Hf, cbuf, b1,b2,b3,bd, bar);

  acro_persist<<<256,512,0,stream>>>(W1f, W2f, W3f, Wdf, Xb1f, Hf,
                                     b1, b2, b3, bd, rseq, out, cn, gn, bar);
}

// Round 3
// 4821.756 us; speedup vs baseline: 1.0477x; 1.0477x over previous
//
#include <hip/hip_runtime.h>

#define TT 128
#define INF 171

typedef _Float16 half8 __attribute__((ext_vector_type(8)));
typedef float floatx4 __attribute__((ext_vector_type(4)));
typedef unsigned short u16;

#define XBSZ 163840   // 8 btiles * 40 kc * 512
#define HSZ  131072   // 8 btiles * 32 kc * 512

__device__ __forceinline__ u16 f2h(float f){
  _Float16 h = (_Float16)f;
  return __builtin_bit_cast(u16, h);
}
__device__ __forceinline__ float sigm(float x){ return 1.f/(1.f+__expf(-x)); }
__device__ __forceinline__ float tanh_(float x){ return 1.f - 2.f/(__expf(2.f*x)+1.f); }

// coherent (L1+L2-bypass, LLC-visible) scatter store of one fp16 value
// layout: [btile][kchunk(nch)][lane(64)][8] ; lane = ((k>>3)&3)*16 + (b&15), elem = k&7
__device__ __forceinline__ void scat_coh(u16* buf, int nch, int b, int k, u16 v){
  u16* p = buf + (size_t)((((b>>4)*nch + (k>>5))*4 + ((k>>3)&3))*16 + (b&15))*8 + (k&7);
  unsigned int vv = v;
  asm volatile("global_store_short %0, %1, off sc0 sc1" :: "v"(p), "v"(vv) : "memory");
}
// coherent 16B load (bypasses L1+L2, reads current LLC truth)
__device__ __forceinline__ void ld16_coh(half8& d, const u16* p){
  asm volatile("global_load_dwordx4 %0, %1, off sc0 sc1" : "=&v"(d) : "v"(p) : "memory");
}

// ---------------- weight prep (fragment-swizzled fp16) ----------------
__global__ __launch_bounds__(256) void prep_w1f(const float* __restrict__ Wih1,
    const float* __restrict__ Whh1, u16* __restrict__ Wf){
  int u = blockIdx.x*256 + threadIdx.x;          // exactly 655360 units
  int tile = u / 2560;
  int r = u - tile*2560;
  int kc = r >> 6, l = r & 63;
  int row = (tile>>6)*1024 + (tile&63)*16 + (l&15);
  int k0 = kc*32 + ((l>>4)<<3);
  half8 hv;
  #pragma unroll
  for (int e=0;e<8;e++){
    int k = k0+e;
    float w = 0.f;
    if (k < 171)       w = Wih1[(size_t)row*171 + k];
    else if (k < 1195) w = Whh1[(size_t)row*1024 + (k-171)];
    hv[e] = (_Float16)w;
  }
  *(half8*)&Wf[(size_t)(tile*40 + kc)*512 + (size_t)l*8] = hv;
}

__global__ __launch_bounds__(256) void prep_w23f(const float* __restrict__ Wih2,
    const float* __restrict__ Whh2, const float* __restrict__ Wih3,
    const float* __restrict__ Whh3, u16* __restrict__ W2f, u16* __restrict__ W3f){
  int u = blockIdx.x*256 + threadIdx.x;          // exactly 1048576 units
  int tile = u >> 12;
  int r = u & 4095;
  int kc = r >> 6, l = r & 63;
  int row = (tile>>6)*1024 + (tile&63)*16 + (l&15);
  int k0 = kc*32 + ((l>>4)<<3);
  half8 h2, h3;
  #pragma unroll
  for (int e=0;e<8;e++){
    int k = k0+e;
    size_t si = (size_t)row*1024 + (k & 1023);
    h2[e] = (_Float16)((k < 1024) ? Wih2[si] : Whh2[si]);
    h3[e] = (_Float16)((k < 1024) ? Wih3[si] : Whh3[si]);
  }
  size_t base = (size_t)(tile*64 + kc)*512 + (size_t)l*8;
  *(half8*)&W2f[base] = h2;
  *(half8*)&W3f[base] = h3;
}

__global__ __launch_bounds__(256) void prep_wdecf(const float* __restrict__ Wdec,
    u16* __restrict__ Wdf){
  int u = blockIdx.x*256 + threadIdx.x;          // exactly 22528 units
  int tile = u / 2048;
  int r = u & 2047;
  int kc = r >> 6, l = r & 63;
  int row = tile*16 + (l&15);
  int k0 = kc*32 + ((l>>4)<<3);
  half8 hv;
  #pragma unroll
  for (int e=0;e<8;e++){
    int k = k0+e;
    hv[e] = (_Float16)((row < 171) ? Wdec[(size_t)row*1024 + k] : 0.f);
  }
  *(half8*)&Wdf[(size_t)(tile*32 + kc)*512 + (size_t)l*8] = hv;
}

// biases + activation-buffer init (+ step-0 frame) + c init + barrier counters
__global__ __launch_bounds__(256) void prep_misc(
    const float* __restrict__ rseq, const int* __restrict__ gnp,
    const float* __restrict__ bih1, const float* __restrict__ bhh1,
    const float* __restrict__ bih2, const float* __restrict__ bhh2,
    const float* __restrict__ bih3, const float* __restrict__ bhh3,
    const float* __restrict__ bdec,
    u16* __restrict__ Xb1f, u16* __restrict__ Hf, float* __restrict__ cbuf,
    float* __restrict__ b1, float* __restrict__ b2, float* __restrict__ b3,
    float* __restrict__ bd, int* __restrict__ bar)
{
  size_t idx = (size_t)blockIdx.x*256 + threadIdx.x;
  if (idx < 327680){                       // Xb1f: 2 parities x [8][40][512]
    int q = (int)(idx / 163840);
    int rem = (int)(idx % 163840);
    int btile = rem / 20480;
    int r2 = rem % 20480;
    int kc = r2 >> 9, r3 = r2 & 511;
    int l = r3 >> 3, e = r3 & 7;
    int b = btile*16 + (l&15);
    int k = kc*32 + ((l>>4)<<3) + e;
    float v = 0.f;
    if (q==0 && k < 171 && *gnp > 0) v = rseq[(size_t)b*TT*INF + k];
    Xb1f[idx] = f2h(v);
    return;
  }
  idx -= 327680;
  if (idx < 786432){ Hf[idx] = 0; return; }        // H0/H1/H2 x 2 parities
  idx -= 786432;
  if (idx < 393216){ cbuf[idx] = 0.f; return; }    // (unused by persist now)
  idx -= 393216;
  if (idx < 12288){
    int which = (int)(idx >> 12), j = (int)(idx & 4095);
    float v = (which==0)? (bih1[j]+bhh1[j]) : (which==1)? (bih2[j]+bhh2[j]) : (bih3[j]+bhh3[j]);
    ((which==0)?b1:(which==1)?b2:b3)[j] = v;
    return;
  }
  idx -= 12288;
  if (idx < 176){ bd[idx] = (idx < 171) ? bdec[idx] : 0.f; return; }
  idx -= 176;
  if (idx < 512) bar[idx] = 0;
}

// ---------------- grid barrier: FENCE-FREE, load-poll ------------------------
// Cross-block data moves via sc0|sc1 (LLC-coherent) accesses -> no L2 wb/inv.
// Every thread drains vmcnt(0) before s_barrier; leader's relaxed LLC atomics
// happen-after. Release detection polls with a relaxed agent LOAD (cheap at
// LLC) instead of fetch_add(0) (which serialized the release atomics behind
// 255 leaders' RMW traffic on one line).
__device__ __forceinline__ void gridbar(int* __restrict__ bar, int bId, int bc, int* s_dead){
  asm volatile("s_waitcnt vmcnt(0)" ::: "memory");
  __syncthreads();
  if (threadIdx.x == 0 && !(*s_dead)){
    int* c1  = &bar[(bId & 7) * 32];
    int* c0  = &bar[288];
    int* gen = &bar[320];
    bool released = false;
    int o1 = __hip_atomic_fetch_add(c1, 1, __ATOMIC_RELAXED, __HIP_MEMORY_SCOPE_AGENT);
    if ((o1 & 31) == 31){
      int o0 = __hip_atomic_fetch_add(c0, 1, __ATOMIC_RELAXED, __HIP_MEMORY_SCOPE_AGENT);
      if ((o0 & 7) == 7){
        __hip_atomic_fetch_add(gen, 1, __ATOMIC_RELAXED, __HIP_MEMORY_SCOPE_AGENT);
        released = true;
      }
    }
    if (!released){
      long long t0 = clock64();
      while (__hip_atomic_load(gen, __ATOMIC_RELAXED, __HIP_MEMORY_SCOPE_AGENT) < bc + 1){
        __builtin_amdgcn_s_sleep(2);
        if (clock64() - t0 > 30000000LL){ *s_dead = 1; break; }  // ~12ms escape
      }
    }
  }
  __syncthreads();
}

// ---------------- coherent global->LDS stage ---------------------------------
// NC chunks, NBC 8KB-beats per chunk; each thread copies 16B per beat.
// asm-issue all loads -> one vmcnt(0) -> sched_barrier(0) -> ds_writes.
template<int NC, int NBC>
__device__ __forceinline__ void stage(const u16* const* srcs, u16* XL, int tid){
  half8 v[NC*NBC];
  #pragma unroll
  for (int c=0;c<NC;c++){
    #pragma unroll
    for (int i=0;i<NBC;i++)
      ld16_coh(v[c*NBC+i], srcs[c] + (size_t)i*4096 + (size_t)tid*8);
  }
  asm volatile("s_waitcnt vmcnt(0)" ::: "memory");
  __builtin_amdgcn_sched_barrier(0);
  #pragma unroll
  for (int c=0;c<NC;c++){
    #pragma unroll
    for (int i=0;i<NBC;i++)
      *(half8*)&XL[(size_t)(c*NBC+i)*4096 + (size_t)tid*8] = v[c*NBC+i];
  }
}

// ---------------- half-K GEMM: W streamed (L2-resident), X from LDS ----------
template<int KHALF, int GS>
__device__ __forceinline__ void gemm_stream(const u16* __restrict__ wp,
    const u16* __restrict__ x0, const u16* __restrict__ x1,
    floatx4& a0, floatx4& a1)
{
  constexpr int NG = KHALF/GS;
  half8 W[2][GS];
  #pragma unroll
  for (int i=0;i<GS;i++)
    W[0][i] = *(const half8*)(wp + (size_t)i*512);
  #pragma unroll
  for (int g8=0; g8<NG; g8++){
    const int cur = g8 & 1, nxt = cur ^ 1;
    if (g8+1 < NG){
      const size_t off = (size_t)(g8+1)*GS*512;
      #pragma unroll
      for (int i=0;i<GS;i++)
        W[nxt][i] = *(const half8*)(wp + off + (size_t)i*512);
    }
    #pragma unroll
    for (int i=0;i<GS;i++){
      half8 xv0 = *(const half8*)(x0 + (size_t)(g8*GS+i)*512);
      half8 xv1 = *(const half8*)(x1 + (size_t)(g8*GS+i)*512);
      a0 = __builtin_amdgcn_mfma_f32_16x16x32_f16(W[cur][i], xv0, a0, 0,0,0);
      a1 = __builtin_amdgcn_mfma_f32_16x16x32_f16(W[cur][i], xv1, a1, 0,0,0);
    }
  }
}

// ---------------- persistent kernel: 256 blocks x 512 threads ----------------
// Block = (js 16 units, nq 32 batch). 8 waves: wave w -> gate (w>>1), K-half (w&1).
// W2 slice (128 VGPR/wave) is PINNED in registers for the whole kernel,
// enforced by an asm keep-alive each iteration (compiler cannot remat the
// loads). W1/W3/Wd stream as plain cached loads: per-XCD streamed set is
// W1 1.25MB + W3 2MB + misc < 4MB L2 -> L2-resident after step 0.
__global__ void __launch_bounds__(512,2) acro_persist(
    const u16* __restrict__ W1f, const u16* __restrict__ W2f,
    const u16* __restrict__ W3f, const u16* __restrict__ Wdf,
    u16* __restrict__ Xb1f, u16* __restrict__ Hf,
    const float* __restrict__ b1, const float* __restrict__ b2,
    const float* __restrict__ b3, const float* __restrict__ bd,
    const float* __restrict__ rseq, float* __restrict__ out,
    const int* __restrict__ cnp, const int* __restrict__ gnp, int* __restrict__ bar)
{
  __shared__ u16 XL[65536];           // 128 KiB activation stage
  __shared__ float gb[8][16][33];     // per-wave partials (+1 pad)
  __shared__ int s_dead;
  const int bId = (int)blockIdx.x;
  const int js = (bId & 7)*8 + ((bId >> 5) & 7);   // 4 nq-siblings share XCD class
  const int nq = (bId >> 3) & 3;
  const int tid = (int)threadIdx.x;
  const int w = tid >> 6, l = tid & 63;
  const int g = w >> 1, hf = w & 1;
  const int l15 = l & 15, lq = l >> 4;
  const int uu = tid >> 5, bq = tid & 31;
  const int jj = js*16 + uu, bgg = nq*32 + bq;
  if (tid == 0) s_dead = 0;
  const int gnv = *gnp;
  int P = *cnp + gnv; if (P < 1) P = 1;
  int bc = 0;                          // barriers completed

  u16* H0[2] = { Hf,          Hf + HSZ   };
  u16* H1[2] = { Hf + 2*HSZ,  Hf + 3*HSZ };
  u16* H2[2] = { Hf + 4*HSZ,  Hf + 5*HSZ };

  // ---- pinned register state: W2 slice, biases, cell state ----
  half8 W2r[32];
  {
    const u16* wp = W2f + ((size_t)(g*64 + js)*64 + (size_t)hf*32)*512 + (size_t)(l<<3);
    #pragma unroll
    for (int i=0;i<32;i++) W2r[i] = *(const half8*)(wp + (size_t)i*512);
  }
  const int dtile = bId >> 2, dq_ = bId & 3;
  const int oo = dtile*16 + uu;
  float bs1[4], bs2[4], bs3[4];
  #pragma unroll
  for (int q=0;q<4;q++){
    bs1[q] = b1[q*1024 + jj];
    bs2[q] = b2[q*1024 + jj];
    bs3[q] = b3[q*1024 + jj];
  }
  const float bdr = (bId < 44) ? bd[oo] : 0.f;   // bd padded to 176
  float c0r = 0.f, c1r = 0.f, c2r = 0.f;

  __syncthreads();
  for (int t=0; t<TT; t++){
    const int pr = t & 1, nx = pr ^ 1;

    // force W2 residency: asm may "modify" the values -> no remat/sink allowed
    #pragma unroll
    for (int i=0;i<32;i++) asm volatile("" : "+v"(W2r[i]));

    // ============ L1: x = [frame | h0(t-1)], 40 kc, W1 streamed (L2-hit) ====
    {
      const u16* xb = Xb1f + (size_t)pr*XBSZ;
      const u16* srcs[2] = { xb + (size_t)(nq*2)*20480, xb + (size_t)(nq*2+1)*20480 };
      stage<2,5>(srcs, XL, tid);
      __syncthreads();
      const u16* wp = W1f + ((size_t)(g*64 + js)*40 + (size_t)hf*20)*512 + (size_t)(l<<3);
      const u16* x0 = XL + (size_t)hf*10240 + (size_t)(l<<3);
      const u16* x1 = x0 + 20480;
      floatx4 a0{}, a1{};
      gemm_stream<20,4>(wp, x0, x1, a0, a1);
      #pragma unroll
      for (int r=0;r<4;r++){
        gb[w][lq*4+r][l15]      = a0[r];
        gb[w][lq*4+r][16 + l15] = a1[r];
      }
      __syncthreads();
      {
        float gi = gb[0][uu][bq] + gb[1][uu][bq] + bs1[0];
        float gf = gb[2][uu][bq] + gb[3][uu][bq] + bs1[1];
        float gg = gb[4][uu][bq] + gb[5][uu][bq] + bs1[2];
        float go = gb[6][uu][bq] + gb[7][uu][bq] + bs1[3];
        float c = sigm(gf)*c0r + sigm(gi)*tanh_(gg);
        c0r = c;
        u16 hb = f2h(sigm(go)*tanh_(c));
        scat_coh(H0[pr], 32, bgg, jj, hb);
        scat_coh(Xb1f + (size_t)nx*XBSZ, 40, bgg, 171 + jj, hb);
      }
    }
    gridbar(bar, bId, bc, &s_dead); bc++;

    // ============ L2: x = [h0(t) | h1(t-1)], 64 kc, W2 PINNED in regs =======
    {
      const u16* xa = H0[pr];
      const u16* xh = H1[nx];
      const u16* srcs[4] = {
        xa + (size_t)(nq*2  )*16384, xa + (size_t)(nq*2+1)*16384,
        xh + (size_t)(nq*2  )*16384, xh + (size_t)(nq*2+1)*16384 };
      stage<4,4>(srcs, XL, tid);
      __syncthreads();
      const u16* x0 = XL + (size_t)hf*32768 + (size_t)(l<<3);
      const u16* x1 = x0 + 16384;
      floatx4 a0{}, a1{};
      #pragma unroll
      for (int i=0;i<32;i++){
        half8 xv0 = *(const half8*)(x0 + (size_t)i*512);
        half8 xv1 = *(const half8*)(x1 + (size_t)i*512);
        a0 = __builtin_amdgcn_mfma_f32_16x16x32_f16(W2r[i], xv0, a0, 0,0,0);
        a1 = __builtin_amdgcn_mfma_f32_16x16x32_f16(W2r[i], xv1, a1, 0,0,0);
      }
      #pragma unroll
      for (int r=0;r<4;r++){
        gb[w][lq*4+r][l15]      = a0[r];
        gb[w][lq*4+r][16 + l15] = a1[r];
      }
      __syncthreads();
      {
        float gi = gb[0][uu][bq] + gb[1][uu][bq] + bs2[0];
        float gf = gb[2][uu][bq] + gb[3][uu][bq] + bs2[1];
        float gg = gb[4][uu][bq] + gb[5][uu][bq] + bs2[2];
        float go = gb[6][uu][bq] + gb[7][uu][bq] + bs2[3];
        float c = sigm(gf)*c1r + sigm(gi)*tanh_(gg);
        c1r = c;
        u16 hb = f2h(sigm(go)*tanh_(c));
        scat_coh(H1[pr], 32, bgg, jj, hb);
      }
    }
    gridbar(bar, bId, bc, &s_dead); bc++;

    // ============ L3: x = [h1(t) | h2(t-1)], 64 kc, W3 streamed (L2-hit) ====
    {
      const u16* xa = H1[pr];
      const u16* xh = H2[nx];
      const u16* srcs[4] = {
        xa + (size_t)(nq*2  )*16384, xa + (size_t)(nq*2+1)*16384,
        xh + (size_t)(nq*2  )*16384, xh + (size_t)(nq*2+1)*16384 };
      stage<4,4>(srcs, XL, tid);
      __syncthreads();
      const u16* wp = W3f + ((size_t)(g*64 + js)*64 + (size_t)hf*32)*512 + (size_t)(l<<3);
      const u16* x0 = XL + (size_t)hf*32768 + (size_t)(l<<3);
      const u16* x1 = x0 + 16384;
      floatx4 a0{}, a1{};
      gemm_stream<32,8>(wp, x0, x1, a0, a1);
      #pragma unroll
      for (int r=0;r<4;r++){
        gb[w][lq*4+r][l15]      = a0[r];
        gb[w][lq*4+r][16 + l15] = a1[r];
      }
      __syncthreads();
      {
        float gi = gb[0][uu][bq] + gb[1][uu][bq] + bs3[0];
        float gf = gb[2][uu][bq] + gb[3][uu][bq] + bs3[1];
        float gg = gb[4][uu][bq] + gb[5][uu][bq] + bs3[2];
        float go = gb[6][uu][bq] + gb[7][uu][bq] + bs3[3];
        float c = sigm(gf)*c2r + sigm(gi)*tanh_(gg);
        c2r = c;
        u16 hb = f2h(sigm(go)*tanh_(c));
        scat_coh(H2[pr], 32, bgg, jj, hb);
      }
    }
    gridbar(bar, bId, bc, &s_dead); bc++;

    // ============ dec: blocks 0..43 = (tile, dq); waves split K 8 ways =======
    if (bId < 44){
      const u16* srcs[2] = { H2[pr] + (size_t)(dq_*2)*16384, H2[pr] + (size_t)(dq_*2+1)*16384 };
      stage<2,4>(srcs, XL, tid);
      __syncthreads();
      const u16* wp = Wdf + (size_t)(dtile*32 + w*4)*512 + (size_t)(l<<3);
      const u16* x0 = XL + (size_t)(w*4)*512 + (size_t)(l<<3);
      const u16* x1 = x0 + 16384;
      floatx4 d0{}, d1{};
      #pragma unroll
      for (int i=0;i<4;i++){
        half8 wv  = *(const half8*)(wp + (size_t)i*512);
        half8 a0v = *(const half8*)(x0 + (size_t)i*512);
        half8 a1v = *(const half8*)(x1 + (size_t)i*512);
        d0 = __builtin_amdgcn_mfma_f32_16x16x32_f16(wv, a0v, d0, 0,0,0);
        d1 = __builtin_amdgcn_mfma_f32_16x16x32_f16(wv, a1v, d1, 0,0,0);
      }
      #pragma unroll
      for (int r=0;r<4;r++){
        gb[w][lq*4+r][l15]      = d0[r];
        gb[w][lq*4+r][16 + l15] = d1[r];
      }
      __syncthreads();
      const int nf = (((t+1) % P) < gnv) ? 1 : 0;
      if (oo < 171){
        float v = bdr;
        #pragma unroll
        for (int i=0;i<8;i++) v += gb[i][uu][bq];
        int b = dq_*32 + bq;
        out[((size_t)b*TT + t)*INF + oo] = v;
        if (t+1 < TT){
          float src = nf ? rseq[((size_t)b*TT + (t+1))*INF + oo] : v;
          scat_coh(Xb1f + (size_t)nx*XBSZ, 40, b, oo, f2h(src));
        }
      }
    }
    gridbar(bar, bId, bc, &s_dead); bc++;
  }
}

// ---------------- host ----------------
extern "C" void kernel_launch(void* const* d_in, const int* in_sizes, int n_in,
                              void* d_out, int out_size, void* d_ws, size_t ws_size,
                              hipStream_t stream)
{
  const float* rseq = (const float*)d_in[0];
  const float* Wih1 = (const float*)d_in[1];
  const float* Whh1 = (const float*)d_in[2];
  const float* bih1 = (const float*)d_in[3];
  const float* bhh1 = (const float*)d_in[4];
  const float* Wih2 = (const float*)d_in[5];
  const float* Whh2 = (const float*)d_in[6];
  const float* bih2 = (const float*)d_in[7];
  const float* bhh2 = (const float*)d_in[8];
  const float* Wih3 = (const float*)d_in[9];
  const float* Whh3 = (const float*)d_in[10];
  const float* bih3 = (const float*)d_in[11];
  const float* bhh3 = (const float*)d_in[12];
  const float* Wdec = (const float*)d_in[13];
  const float* bdec = (const float*)d_in[14];
  const int* cn = (const int*)d_in[15];
  const int* gn = (const int*)d_in[16];
  float* out = (float*)d_out;

  char* p = (char*)d_ws;
  auto take = [&](size_t n){ void* r = (void*)p; p += (n + 255) & ~(size_t)255; return r; };
  u16* W1f  = (u16*)take(5242880UL*2);      // 256*40*512
  u16* W2f  = (u16*)take(8388608UL*2);      // 256*64*512
  u16* W3f  = (u16*)take(8388608UL*2);
  u16* Wdf  = (u16*)take(180224UL*2);       // 11*32*512
  u16* Xb1f = (u16*)take(327680UL*2);       // 2 parities x [8][40][512]
  u16* Hf   = (u16*)take(786432UL*2);       // 6 x [8][32][512]
  float* cbuf = (float*)take(393216UL*4);   // (kept for prep_misc; unused by persist)
  float* b1 = (float*)take(4096*4);
  float* b2 = (float*)take(4096*4);
  float* b3 = (float*)take(4096*4);
  float* bd = (float*)take(176*4);
  int* bar  = (int*)take(512*4);
  if ((size_t)(p - (char*)d_ws) > ws_size) return;

  prep_w1f  <<<2560,256,0,stream>>>(Wih1, Whh1, W1f);
  prep_w23f <<<4096,256,0,stream>>>(Wih2, Whh2, Wih3, Whh3, W2f, W3f);
  prep_wdecf<<<88,  256,0,stream>>>(Wdec, Wdf);
  prep_misc <<<5939,256,0,stream>>>(rseq, gn, bih1,bhh1,bih2,bhh2,bih3,bhh3,bdec,
                                    Xb1f, Hf, cbuf, b1,b2,b3,bd, bar);

  acro_persist<<<256,512,0,stream>>>(W1f, W2f, W3f, Wdf, Xb1f, Hf,
                                     b1, b2, b3, bd, rseq, out, cn, gn, bar);
}

// Round 4
// 4451.226 us; speedup vs baseline: 1.1350x; 1.0832x over previous
//
#include <hip/hip_runtime.h>

#define TT 128
#define INF 171

typedef _Float16 half8 __attribute__((ext_vector_type(8)));
typedef float floatx4 __attribute__((ext_vector_type(4)));
typedef unsigned short u16;

#define XBSZ 163840   // 8 btiles * 40 kc * 512
#define HSZ  131072   // 8 btiles * 32 kc * 512

#define WAITV(n) asm volatile("s_waitcnt vmcnt(" #n ")" ::: "memory")

__device__ __forceinline__ u16 f2h(float f){
  _Float16 h = (_Float16)f;
  return __builtin_bit_cast(u16, h);
}
__device__ __forceinline__ float sigm(float x){ return 1.f/(1.f+__expf(-x)); }
__device__ __forceinline__ float tanh_(float x){ return 1.f - 2.f/(__expf(2.f*x)+1.f); }

// coherent (L1+L2-bypass, LLC-visible) scatter store of one fp16 value
// layout: [btile][kchunk(nch)][lane(64)][8] ; lane = ((k>>3)&3)*16 + (b&15), elem = k&7
__device__ __forceinline__ void scat_coh(u16* buf, int nch, int b, int k, u16 v){
  u16* p = buf + (size_t)((((b>>4)*nch + (k>>5))*4 + ((k>>3)&3))*16 + (b&15))*8 + (k&7);
  unsigned int vv = v;
  asm volatile("global_store_short %0, %1, off sc0 sc1" :: "v"(p), "v"(vv) : "memory");
}
// coherent 16B load (bypasses L1+L2, reads current LLC truth)
__device__ __forceinline__ void ld16_coh(half8& d, const u16* p){
  asm volatile("global_load_dwordx4 %0, %1, off sc0 sc1" : "=&v"(d) : "v"(p) : "memory");
}

// issue NB beats from each of two chunk pointers (beats beat0..beat0+NB-1)
template<int NB>
__device__ __forceinline__ void issue_pair(const u16* s0, const u16* s1,
    half8* v, int tid, int beat0){
  #pragma unroll
  for (int i=0;i<NB;i++) ld16_coh(v[i],    s0 + (size_t)(beat0+i)*4096 + (size_t)tid*8);
  #pragma unroll
  for (int i=0;i<NB;i++) ld16_coh(v[NB+i], s1 + (size_t)(beat0+i)*4096 + (size_t)tid*8);
}

// ---------------- weight prep (fragment-swizzled fp16) ----------------
__global__ __launch_bounds__(256) void prep_w1f(const float* __restrict__ Wih1,
    const float* __restrict__ Whh1, u16* __restrict__ Wf){
  int u = blockIdx.x*256 + threadIdx.x;          // exactly 655360 units
  int tile = u / 2560;
  int r = u - tile*2560;
  int kc = r >> 6, l = r & 63;
  int row = (tile>>6)*1024 + (tile&63)*16 + (l&15);
  int k0 = kc*32 + ((l>>4)<<3);
  half8 hv;
  #pragma unroll
  for (int e=0;e<8;e++){
    int k = k0+e;
    float w = 0.f;
    if (k < 171)       w = Wih1[(size_t)row*171 + k];
    else if (k < 1195) w = Whh1[(size_t)row*1024 + (k-171)];
    hv[e] = (_Float16)w;
  }
  *(half8*)&Wf[(size_t)(tile*40 + kc)*512 + (size_t)l*8] = hv;
}

__global__ __launch_bounds__(256) void prep_w23f(const float* __restrict__ Wih2,
    const float* __restrict__ Whh2, const float* __restrict__ Wih3,
    const float* __restrict__ Whh3, u16* __restrict__ W2f, u16* __restrict__ W3f){
  int u = blockIdx.x*256 + threadIdx.x;          // exactly 1048576 units
  int tile = u >> 12;
  int r = u & 4095;
  int kc = r >> 6, l = r & 63;
  int row = (tile>>6)*1024 + (tile&63)*16 + (l&15);
  int k0 = kc*32 + ((l>>4)<<3);
  half8 h2, h3;
  #pragma unroll
  for (int e=0;e<8;e++){
    int k = k0+e;
    size_t si = (size_t)row*1024 + (k & 1023);
    h2[e] = (_Float16)((k < 1024) ? Wih2[si] : Whh2[si]);
    h3[e] = (_Float16)((k < 1024) ? Wih3[si] : Whh3[si]);
  }
  size_t base = (size_t)(tile*64 + kc)*512 + (size_t)l*8;
  *(half8*)&W2f[base] = h2;
  *(half8*)&W3f[base] = h3;
}

__global__ __launch_bounds__(256) void prep_wdecf(const float* __restrict__ Wdec,
    u16* __restrict__ Wdf){
  int u = blockIdx.x*256 + threadIdx.x;          // exactly 22528 units
  int tile = u / 2048;
  int r = u & 2047;
  int kc = r >> 6, l = r & 63;
  int row = tile*16 + (l&15);
  int k0 = kc*32 + ((l>>4)<<3);
  half8 hv;
  #pragma unroll
  for (int e=0;e<8;e++){
    int k = k0+e;
    hv[e] = (_Float16)((row < 171) ? Wdec[(size_t)row*1024 + k] : 0.f);
  }
  *(half8*)&Wdf[(size_t)(tile*32 + kc)*512 + (size_t)l*8] = hv;
}

// biases + activation-buffer init (+ step-0 frame) + c init + barrier counters
__global__ __launch_bounds__(256) void prep_misc(
    const float* __restrict__ rseq, const int* __restrict__ gnp,
    const float* __restrict__ bih1, const float* __restrict__ bhh1,
    const float* __restrict__ bih2, const float* __restrict__ bhh2,
    const float* __restrict__ bih3, const float* __restrict__ bhh3,
    const float* __restrict__ bdec,
    u16* __restrict__ Xb1f, u16* __restrict__ Hf, float* __restrict__ cbuf,
    float* __restrict__ b1, float* __restrict__ b2, float* __restrict__ b3,
    float* __restrict__ bd, int* __restrict__ bar)
{
  size_t idx = (size_t)blockIdx.x*256 + threadIdx.x;
  if (idx < 327680){                       // Xb1f: 2 parities x [8][40][512]
    int q = (int)(idx / 163840);
    int rem = (int)(idx % 163840);
    int btile = rem / 20480;
    int r2 = rem % 20480;
    int kc = r2 >> 9, r3 = r2 & 511;
    int l = r3 >> 3, e = r3 & 7;
    int b = btile*16 + (l&15);
    int k = kc*32 + ((l>>4)<<3) + e;
    float v = 0.f;
    if (q==0 && k < 171 && *gnp > 0) v = rseq[(size_t)b*TT*INF + k];
    Xb1f[idx] = f2h(v);
    return;
  }
  idx -= 327680;
  if (idx < 786432){ Hf[idx] = 0; return; }        // H0/H1/H2 x 2 parities
  idx -= 786432;
  if (idx < 393216){ cbuf[idx] = 0.f; return; }    // (unused by persist now)
  idx -= 393216;
  if (idx < 12288){
    int which = (int)(idx >> 12), j = (int)(idx & 4095);
    float v = (which==0)? (bih1[j]+bhh1[j]) : (which==1)? (bih2[j]+bhh2[j]) : (bih3[j]+bhh3[j]);
    ((which==0)?b1:(which==1)?b2:b3)[j] = v;
    return;
  }
  idx -= 12288;
  if (idx < 176){ bd[idx] = (idx < 171) ? bdec[idx] : 0.f; return; }
  idx -= 176;
  if (idx < 512) bar[idx] = 0;
}

// ---------------- PER-CLASS barrier (64 blocks), fence-free ------------------
// The 4 batch-classes (nq) are fully independent: each block only touches
// btiles {2nq,2nq+1} of Xb1f/Hf and batches nq*32..+31 of out. Barrier scope
// is therefore 64 blocks, not 256. Two 32-arrival lines per class; the 32nd
// arriver on each line bumps the class gen; release when gen reaches 2*(bc+1).
// Caller drains stores (counted WAITV) BEFORE calling.
__device__ __forceinline__ void gridbar(int* __restrict__ bar, int cls, int hv,
                                        int bc, int* s_dead){
  __syncthreads();
  if (threadIdx.x == 0 && !(*s_dead)){
    int* arr = &bar[cls*64 + hv*32];
    int* gen = &bar[256 + cls*32];
    bool released = false;
    int o = __hip_atomic_fetch_add(arr, 1, __ATOMIC_RELAXED, __HIP_MEMORY_SCOPE_AGENT);
    if ((o & 31) == 31){
      int og = __hip_atomic_fetch_add(gen, 1, __ATOMIC_RELAXED, __HIP_MEMORY_SCOPE_AGENT);
      released = (og & 1) == 1;
    }
    if (!released){
      long long t0 = clock64();
      while (__hip_atomic_load(gen, __ATOMIC_RELAXED, __HIP_MEMORY_SCOPE_AGENT) < 2*(bc+1)){
        __builtin_amdgcn_s_sleep(2);
        if (clock64() - t0 > 30000000LL){ *s_dead = 1; break; }  // ~12ms escape
      }
    }
  }
  __syncthreads();
}

// ---------------- half-K GEMM: W streamed (L2), X from LDS -------------------
template<int KHALF, int GS>
__device__ __forceinline__ void gemm_stream(const u16* __restrict__ wp,
    const u16* __restrict__ x0, const u16* __restrict__ x1,
    floatx4& a0, floatx4& a1)
{
  constexpr int NG = KHALF/GS;
  half8 W[2][GS];
  #pragma unroll
  for (int i=0;i<GS;i++)
    W[0][i] = *(const half8*)(wp + (size_t)i*512);
  #pragma unroll
  for (int g8=0; g8<NG; g8++){
    const int cur = g8 & 1, nxt = cur ^ 1;
    if (g8+1 < NG){
      const size_t off = (size_t)(g8+1)*GS*512;
      #pragma unroll
      for (int i=0;i<GS;i++)
        W[nxt][i] = *(const half8*)(wp + off + (size_t)i*512);
    }
    #pragma unroll
    for (int i=0;i<GS;i++){
      half8 xv0 = *(const half8*)(x0 + (size_t)(g8*GS+i)*512);
      half8 xv1 = *(const half8*)(x1 + (size_t)(g8*GS+i)*512);
      a0 = __builtin_amdgcn_mfma_f32_16x16x32_f16(W[cur][i], xv0, a0, 0,0,0);
      a1 = __builtin_amdgcn_mfma_f32_16x16x32_f16(W[cur][i], xv1, a1, 0,0,0);
    }
  }
}

// ---------------- persistent kernel: 256 blocks x 512 threads ----------------
// Block = (js 16 units, nq 32 batch). 8 waves: wave w -> gate (w>>1), K-half (w&1).
// 4 independent batch-classes (cls = nq, 64 blocks each) with per-class
// barriers. Stale halves of every stage are prefetched into registers BEFORE
// the preceding barrier (counted vmcnt(8) leaves them in flight; they land
// during the barrier spin). dec remapped so dq == nq (class-local).
__global__ void __launch_bounds__(512,2) acro_persist(
    const u16* __restrict__ W1f, const u16* __restrict__ W2f,
    const u16* __restrict__ W3f, const u16* __restrict__ Wdf,
    u16* __restrict__ Xb1f, u16* __restrict__ Hf,
    const float* __restrict__ b1, const float* __restrict__ b2,
    const float* __restrict__ b3, const float* __restrict__ bd,
    const float* __restrict__ rseq, float* __restrict__ out,
    const int* __restrict__ cnp, const int* __restrict__ gnp, int* __restrict__ bar)
{
  __shared__ u16 XL[65536];           // 128 KiB activation stage
  __shared__ float gb[8][16][33];     // per-wave partials (+1 pad)
  __shared__ int s_dead;
  const int bId = (int)blockIdx.x;
  const int js = (bId & 7)*8 + ((bId >> 5) & 7);   // 4 nq-siblings share XCD class
  const int nq = (bId >> 3) & 3;
  const int bh = (bId >> 5) & 1;                   // arrival line within class
  const int tid = (int)threadIdx.x;
  const int w = tid >> 6, l = tid & 63;
  const int g = w >> 1, hf = w & 1;
  const int l15 = l & 15, lq = l >> 4;
  const int uu = tid >> 5, bq = tid & 31;
  const int jj = js*16 + uu, bgg = nq*32 + bq;
  if (tid == 0) s_dead = 0;
  const int gnv = *gnp;
  int P = *cnp + gnv; if (P < 1) P = 1;
  int bc = 0;                          // barriers completed

  u16* H0[2] = { Hf,          Hf + HSZ   };
  u16* H1[2] = { Hf + 2*HSZ,  Hf + 3*HSZ };
  u16* H2[2] = { Hf + 4*HSZ,  Hf + 5*HSZ };

  float bs1[4], bs2[4], bs3[4];
  #pragma unroll
  for (int q=0;q<4;q++){
    bs1[q] = b1[q*1024 + jj];
    bs2[q] = b2[q*1024 + jj];
    bs3[q] = b3[q*1024 + jj];
  }
  const float bdr = (js < 11) ? bd[js*16 + uu] : 0.f;   // bd padded to 176
  const int oo = js*16 + uu;
  float c0r = 0.f, c1r = 0.f, c2r = 0.f;

  // prefetch registers (statically indexed only)
  half8 pf1[8], pf2[8], pf3[8];
  // pre-loop: prefetch L1(t=0) stale beats (kc 8..39 of both btiles, parity 0)
  issue_pair<4>(Xb1f + (size_t)(nq*2  )*20480,
                Xb1f + (size_t)(nq*2+1)*20480, pf1, tid, 1);

  __syncthreads();
  for (int t=0; t<TT; t++){
    const int pr = t & 1, nx = pr ^ 1;

    // ============ L1: x = [frame | h0(t-1)], 40 kc; beats 1..4 prefetched ====
    {
      const u16* xb = Xb1f + (size_t)pr*XBSZ;
      half8 fr0, fr1;   // beat 0 of each btile (frame part, fresh from dec)
      ld16_coh(fr0, xb + (size_t)(nq*2  )*20480 + (size_t)tid*8);
      ld16_coh(fr1, xb + (size_t)(nq*2+1)*20480 + (size_t)tid*8);
      WAITV(0);
      __builtin_amdgcn_sched_barrier(0);
      *(half8*)&XL[(size_t)tid*8] = fr0;
      *(half8*)&XL[(size_t)5*4096 + (size_t)tid*8] = fr1;
      #pragma unroll
      for (int i=0;i<4;i++){
        *(half8*)&XL[(size_t)(1+i)*4096 + (size_t)tid*8] = pf1[i];
        *(half8*)&XL[(size_t)(6+i)*4096 + (size_t)tid*8] = pf1[4+i];
      }
      __syncthreads();
      const u16* wp = W1f + ((size_t)(g*64 + js)*40 + (size_t)hf*20)*512 + (size_t)(l<<3);
      const u16* x0 = XL + (size_t)hf*10240 + (size_t)(l<<3);
      const u16* x1 = x0 + 20480;
      floatx4 a0{}, a1{};
      gemm_stream<20,4>(wp, x0, x1, a0, a1);
      #pragma unroll
      for (int r=0;r<4;r++){
        gb[w][lq*4+r][l15]      = a0[r];
        gb[w][lq*4+r][16 + l15] = a1[r];
      }
      __syncthreads();
      {
        float gi = gb[0][uu][bq] + gb[1][uu][bq] + bs1[0];
        float gf = gb[2][uu][bq] + gb[3][uu][bq] + bs1[1];
        float gg = gb[4][uu][bq] + gb[5][uu][bq] + bs1[2];
        float go = gb[6][uu][bq] + gb[7][uu][bq] + bs1[3];
        float c = sigm(gf)*c0r + sigm(gi)*tanh_(gg);
        c0r = c;
        u16 hb = f2h(sigm(go)*tanh_(c));
        scat_coh(H0[pr], 32, bgg, jj, hb);
        scat_coh(Xb1f + (size_t)nx*XBSZ, 40, bgg, 171 + jj, hb);
      }
      // prefetch L2's stale half: H1[nx] (written at step t-1, stable)
      issue_pair<4>(H1[nx] + (size_t)(nq*2  )*16384,
                    H1[nx] + (size_t)(nq*2+1)*16384, pf2, tid, 0);
    }
    WAITV(8);                           // drain stores; pf2 rides the barrier
    gridbar(bar, nq, bh, bc, &s_dead); bc++;

    // ============ L2: x = [h0(t) | h1(t-1)], W2 streamed =====================
    {
      half8 fr[8];
      issue_pair<4>(H0[pr] + (size_t)(nq*2  )*16384,
                    H0[pr] + (size_t)(nq*2+1)*16384, fr, tid, 0);
      WAITV(0);
      __builtin_amdgcn_sched_barrier(0);
      #pragma unroll
      for (int i=0;i<8;i++) *(half8*)&XL[(size_t)i*4096 + (size_t)tid*8] = fr[i];
      #pragma unroll
      for (int i=0;i<8;i++) *(half8*)&XL[32768 + (size_t)i*4096 + (size_t)tid*8] = pf2[i];
      __syncthreads();
      const u16* wp = W2f + ((size_t)(g*64 + js)*64 + (size_t)hf*32)*512 + (size_t)(l<<3);
      const u16* x0 = XL + (size_t)hf*32768 + (size_t)(l<<3);
      const u16* x1 = x0 + 16384;
      floatx4 a0{}, a1{};
      gemm_stream<32,8>(wp, x0, x1, a0, a1);
      #pragma unroll
      for (int r=0;r<4;r++){
        gb[w][lq*4+r][l15]      = a0[r];
        gb[w][lq*4+r][16 + l15] = a1[r];
      }
      __syncthreads();
      {
        float gi = gb[0][uu][bq] + gb[1][uu][bq] + bs2[0];
        float gf = gb[2][uu][bq] + gb[3][uu][bq] + bs2[1];
        float gg = gb[4][uu][bq] + gb[5][uu][bq] + bs2[2];
        float go = gb[6][uu][bq] + gb[7][uu][bq] + bs2[3];
        float c = sigm(gf)*c1r + sigm(gi)*tanh_(gg);
        c1r = c;
        u16 hb = f2h(sigm(go)*tanh_(c));
        scat_coh(H1[pr], 32, bgg, jj, hb);
      }
      // prefetch L3's stale half: H2[nx]
      issue_pair<4>(H2[nx] + (size_t)(nq*2  )*16384,
                    H2[nx] + (size_t)(nq*2+1)*16384, pf3, tid, 0);
    }
    WAITV(8);
    gridbar(bar, nq, bh, bc, &s_dead); bc++;

    // ============ L3: x = [h1(t) | h2(t-1)], W3 streamed =====================
    {
      half8 fr[8];
      issue_pair<4>(H1[pr] + (size_t)(nq*2  )*16384,
                    H1[pr] + (size_t)(nq*2+1)*16384, fr, tid, 0);
      WAITV(0);
      __builtin_amdgcn_sched_barrier(0);
      #pragma unroll
      for (int i=0;i<8;i++) *(half8*)&XL[(size_t)i*4096 + (size_t)tid*8] = fr[i];
      #pragma unroll
      for (int i=0;i<8;i++) *(half8*)&XL[32768 + (size_t)i*4096 + (size_t)tid*8] = pf3[i];
      __syncthreads();
      const u16* wp = W3f + ((size_t)(g*64 + js)*64 + (size_t)hf*32)*512 + (size_t)(l<<3);
      const u16* x0 = XL + (size_t)hf*32768 + (size_t)(l<<3);
      const u16* x1 = x0 + 16384;
      floatx4 a0{}, a1{};
      gemm_stream<32,8>(wp, x0, x1, a0, a1);
      #pragma unroll
      for (int r=0;r<4;r++){
        gb[w][lq*4+r][l15]      = a0[r];
        gb[w][lq*4+r][16 + l15] = a1[r];
      }
      __syncthreads();
      {
        float gi = gb[0][uu][bq] + gb[1][uu][bq] + bs3[0];
        float gf = gb[2][uu][bq] + gb[3][uu][bq] + bs3[1];
        float gg = gb[4][uu][bq] + gb[5][uu][bq] + bs3[2];
        float go = gb[6][uu][bq] + gb[7][uu][bq] + bs3[3];
        float c = sigm(gf)*c2r + sigm(gi)*tanh_(gg);
        c2r = c;
        u16 hb = f2h(sigm(go)*tanh_(c));
        scat_coh(H2[pr], 32, bgg, jj, hb);
      }
    }
    WAITV(0);
    gridbar(bar, nq, bh, bc, &s_dead); bc++;

    // ============ dec: class-local, js<11 -> (dtile=js, dq=nq) ===============
    if (js < 11){
      half8 fd[8];
      issue_pair<4>(H2[pr] + (size_t)(nq*2  )*16384,
                    H2[pr] + (size_t)(nq*2+1)*16384, fd, tid, 0);
      WAITV(0);
      __builtin_amdgcn_sched_barrier(0);
      #pragma unroll
      for (int i=0;i<8;i++) *(half8*)&XL[(size_t)i*4096 + (size_t)tid*8] = fd[i];
      __syncthreads();
      const u16* wp = Wdf + (size_t)(js*32 + w*4)*512 + (size_t)(l<<3);
      const u16* x0 = XL + (size_t)(w*4)*512 + (size_t)(l<<3);
      const u16* x1 = x0 + 16384;
      floatx4 d0{}, d1{};
      #pragma unroll
      for (int i=0;i<4;i++){
        half8 wv  = *(const half8*)(wp + (size_t)i*512);
        half8 a0v = *(const half8*)(x0 + (size_t)i*512);
        half8 a1v = *(const half8*)(x1 + (size_t)i*512);
        d0 = __builtin_amdgcn_mfma_f32_16x16x32_f16(wv, a0v, d0, 0,0,0);
        d1 = __builtin_amdgcn_mfma_f32_16x16x32_f16(wv, a1v, d1, 0,0,0);
      }
      #pragma unroll
      for (int r=0;r<4;r++){
        gb[w][lq*4+r][l15]      = d0[r];
        gb[w][lq*4+r][16 + l15] = d1[r];
      }
      __syncthreads();
      const int nf = (((t+1) % P) < gnv) ? 1 : 0;
      if (oo < 171){
        float v = bdr;
        #pragma unroll
        for (int i=0;i<8;i++) v += gb[i][uu][bq];
        out[((size_t)bgg*TT + t)*INF + oo] = v;
        if (t+1 < TT){
          float src = nf ? rseq[((size_t)bgg*TT + (t+1))*INF + oo] : v;
          scat_coh(Xb1f + (size_t)nx*XBSZ, 40, bgg, oo, f2h(src));
        }
      }
    }
    // all blocks: prefetch L1(t+1) stale beats (h-part, written at seg 1)
    if (t+1 < TT){
      const u16* xbn = Xb1f + (size_t)nx*XBSZ;
      issue_pair<4>(xbn + (size_t)(nq*2  )*20480,
                    xbn + (size_t)(nq*2+1)*20480, pf1, tid, 1);
      WAITV(8);
    } else {
      WAITV(0);
    }
    gridbar(bar, nq, bh, bc, &s_dead); bc++;
  }
}

// ---------------- host ----------------
extern "C" void kernel_launch(void* const* d_in, const int* in_sizes, int n_in,
                              void* d_out, int out_size, void* d_ws, size_t ws_size,
                              hipStream_t stream)
{
  const float* rseq = (const float*)d_in[0];
  const float* Wih1 = (const float*)d_in[1];
  const float* Whh1 = (const float*)d_in[2];
  const float* bih1 = (const float*)d_in[3];
  const float* bhh1 = (const float*)d_in[4];
  const float* Wih2 = (const float*)d_in[5];
  const float* Whh2 = (const float*)d_in[6];
  const float* bih2 = (const float*)d_in[7];
  const float* bhh2 = (const float*)d_in[8];
  const float* Wih3 = (const float*)d_in[9];
  const float* Whh3 = (const float*)d_in[10];
  const float* bih3 = (const float*)d_in[11];
  const float* bhh3 = (const float*)d_in[12];
  const float* Wdec = (const float*)d_in[13];
  const float* bdec = (const float*)d_in[14];
  const int* cn = (const int*)d_in[15];
  const int* gn = (const int*)d_in[16];
  float* out = (float*)d_out;

  char* p = (char*)d_ws;
  auto take = [&](size_t n){ void* r = (void*)p; p += (n + 255) & ~(size_t)255; return r; };
  u16* W1f  = (u16*)take(5242880UL*2);      // 256*40*512
  u16* W2f  = (u16*)take(8388608UL*2);      // 256*64*512
  u16* W3f  = (u16*)take(8388608UL*2);
  u16* Wdf  = (u16*)take(180224UL*2);       // 11*32*512
  u16* Xb1f = (u16*)take(327680UL*2);       // 2 parities x [8][40][512]
  u16* Hf   = (u16*)take(786432UL*2);       // 6 x [8][32][512]
  float* cbuf = (float*)take(393216UL*4);   // (kept for prep_misc; unused by persist)
  float* b1 = (float*)take(4096*4);
  float* b2 = (float*)take(4096*4);
  float* b3 = (float*)take(4096*4);
  float* bd = (float*)take(176*4);
  int* bar  = (int*)take(512*4);
  if ((size_t)(p - (char*)d_ws) > ws_size) return;

  prep_w1f  <<<2560,256,0,stream>>>(Wih1, Whh1, W1f);
  prep_w23f <<<4096,256,0,stream>>>(Wih2, Whh2, Wih3, Whh3, W2f, W3f);
  prep_wdecf<<<88,  256,0,stream>>>(Wdec, Wdf);
  prep_misc <<<5939,256,0,stream>>>(rseq, gn, bih1,bhh1,bih2,bhh2,bih3,bhh3,bdec,
                                    Xb1f, Hf, cbuf, b1,b2,b3,bd, bar);

  acro_persist<<<256,512,0,stream>>>(W1f, W2f, W3f, Wdf, Xb1f, Hf,
                                     b1, b2, b3, bd, rseq, out, cn, gn, bar);
}